// Round 5
// baseline (81.195 us; speedup 1.0000x reference)
//
#include <hip/hip_runtime.h>

typedef float f32x4 __attribute__((ext_vector_type(4)));

__device__ __forceinline__ void lif_step(const f32x4& dec, f32x4& v,
                                         const f32x4& xt, f32x4& s) {
#pragma unroll
    for (int k = 0; k < 4; ++k) {
        // v = decay*v + x (round-per-op, no FMA contraction: match numpy)
        v[k] = __fadd_rn(__fmul_rn(dec[k], v[k]), xt[k]);
        s[k] = (v[k] >= 1.0f) ? 1.0f : 0.0f;
        v[k] = (v[k] >= 1.0f) ? 0.0f : v[k];
    }
}

// LIF forward, compile-time T: fully unrolled t-loop with depth-2 load
// pipeline so each wave always has the next x-load in flight during
// compute+store of the current step. NT loads/stores (pure streams).
template <int TT>
__global__ __launch_bounds__(256) void lif_fwd_tmpl(
    const f32x4* __restrict__ x,      // [TT, n4]
    const f32x4* __restrict__ w4,     // [c4]
    const f32x4* __restrict__ v0,     // [n4]
    f32x4* __restrict__ out,          // [TT, n4]
    int n4, int c4m)                  // c4m = c4-1 (pow2 mask)
{
    int i = blockIdx.x * blockDim.x + threadIdx.x;
    if (i >= n4) return;

    // issue first x-load before the expf prologue
    f32x4 xt = __builtin_nontemporal_load(&x[i]);
    f32x4 v  = v0[i];

    f32x4 wv = w4[i & c4m];
    f32x4 dec;
#pragma unroll
    for (int k = 0; k < 4; ++k)
        dec[k] = 1.0f - 1.0f / (1.0f + expf(-wv[k]));

#pragma unroll
    for (int t = 0; t < TT; ++t) {
        f32x4 xn;
        if (t + 1 < TT)
            xn = __builtin_nontemporal_load(&x[(size_t)(t + 1) * n4 + i]);
        f32x4 s;
        lif_step(dec, v, xt, s);
        __builtin_nontemporal_store(s, &out[(size_t)t * n4 + i]);
        xt = xn;
    }
}

// Runtime-T fallback (R4 structure) for unexpected shapes.
__global__ __launch_bounds__(256) void lif_fwd_rt(
    const f32x4* __restrict__ x, const f32x4* __restrict__ w4,
    const f32x4* __restrict__ v0, f32x4* __restrict__ out,
    int n4, int c4, int T)
{
    int i = blockIdx.x * blockDim.x + threadIdx.x;
    if (i >= n4) return;
    f32x4 wv = w4[i % c4];
    f32x4 dec;
#pragma unroll
    for (int k = 0; k < 4; ++k)
        dec[k] = 1.0f - 1.0f / (1.0f + expf(-wv[k]));
    f32x4 v = v0[i];
    for (int t = 0; t < T; ++t) {
        const size_t idx = (size_t)t * n4 + i;
        f32x4 xt = __builtin_nontemporal_load(&x[idx]);
        f32x4 s;
        lif_step(dec, v, xt, s);
        __builtin_nontemporal_store(s, &out[idx]);
    }
}

extern "C" void kernel_launch(void* const* d_in, const int* in_sizes, int n_in,
                              void* d_out, int out_size, void* d_ws, size_t ws_size,
                              hipStream_t stream) {
    const float* x      = (const float*)d_in[0];   // [T,B,S,C]
    const float* w      = (const float*)d_in[1];   // [C]
    const float* v_init = (const float*)d_in[2];   // [B,S,C]
    float* out = (float*)d_out;                    // [T,B,S,C]

    const int C  = in_sizes[1];
    const int N  = in_sizes[2];                    // B*S*C
    const int T  = in_sizes[0] / N;
    const int n4 = N / 4;
    const int c4 = C / 4;

    dim3 block(256);
    dim3 grid((n4 + block.x - 1) / block.x);

    const bool pow2 = (c4 & (c4 - 1)) == 0;
    if (T == 16 && pow2) {
        lif_fwd_tmpl<16><<<grid, block, 0, stream>>>(
            (const f32x4*)x, (const f32x4*)w, (const f32x4*)v_init,
            (f32x4*)out, n4, c4 - 1);
    } else {
        lif_fwd_rt<<<grid, block, 0, stream>>>(
            (const f32x4*)x, (const f32x4*)w, (const f32x4*)v_init,
            (f32x4*)out, n4, c4, T);
    }
}

// Round 6
// 67.830 us; speedup vs baseline: 1.1970x; 1.1970x over previous
//
#include <hip/hip_runtime.h>

typedef float f32x4 __attribute__((ext_vector_type(4)));

// LIF forward: v = decay*v + x[t]; s = (v>=1); hard reset v=0 on spike.
// R4 structure. A/B attribution round: NT on the x loads only (bypass L2 for
// the read stream), NORMAL stores (full-line writes coalesce in L2 — the
// harness fillBuffer sustains 7+ TB/s through this path).
__global__ __launch_bounds__(256) void lif_fwd_kernel(
    const f32x4* __restrict__ x,      // [T, n4]
    const f32x4* __restrict__ w4,     // [c4]
    const f32x4* __restrict__ v0,     // [n4]
    f32x4* __restrict__ out,          // [T, n4]
    int n4, int c4, int T)
{
    int i = blockIdx.x * blockDim.x + threadIdx.x;
    if (i >= n4) return;

    // decay = 1 - sigmoid(w), per channel (once, off the hot path)
    f32x4 wv = w4[i % c4];
    f32x4 dec;
#pragma unroll
    for (int k = 0; k < 4; ++k)
        dec[k] = 1.0f - 1.0f / (1.0f + expf(-wv[k]));

    f32x4 v = v0[i];

    for (int t = 0; t < T; ++t) {
        const size_t idx = (size_t)t * n4 + i;
        f32x4 xt = __builtin_nontemporal_load(&x[idx]);
        f32x4 s;
#pragma unroll
        for (int k = 0; k < 4; ++k) {
            // v = decay*v + x (round-per-op, no FMA contraction: match numpy)
            v[k] = __fadd_rn(__fmul_rn(dec[k], v[k]), xt[k]);
            s[k] = (v[k] >= 1.0f) ? 1.0f : 0.0f;
            v[k] = (v[k] >= 1.0f) ? 0.0f : v[k];
        }
        out[idx] = s;   // normal store: full-line, via L2
    }
}

extern "C" void kernel_launch(void* const* d_in, const int* in_sizes, int n_in,
                              void* d_out, int out_size, void* d_ws, size_t ws_size,
                              hipStream_t stream) {
    const float* x      = (const float*)d_in[0];   // [T,B,S,C]
    const float* w      = (const float*)d_in[1];   // [C]
    const float* v_init = (const float*)d_in[2];   // [B,S,C]
    float* out = (float*)d_out;                    // [T,B,S,C]

    const int C  = in_sizes[1];
    const int N  = in_sizes[2];                    // B*S*C
    const int T  = in_sizes[0] / N;
    const int n4 = N / 4;
    const int c4 = C / 4;

    dim3 block(256);
    dim3 grid((n4 + block.x - 1) / block.x);
    lif_fwd_kernel<<<grid, block, 0, stream>>>(
        (const f32x4*)x, (const f32x4*)w, (const f32x4*)v_init,
        (f32x4*)out, n4, c4, T);
}